// Round 3
// baseline (243.093 us; speedup 1.0000x reference)
//
#include <hip/hip_runtime.h>
#include <math.h>

namespace {

constexpr int kB = 2, kL = 2048, kH = 16, kE = 64;
constexpr int kC  = 32;            // s-steps per chunk
constexpr int kNC = kL / kC;       // 64 chunks per (b,h)
constexpr int kBH = kB * kH;       // 32
constexpr int kRow = kH * kE;      // 1024 floats between consecutive s
constexpr float kScale = 0.125f;   // 1/sqrt(64)
constexpr unsigned kReady = 1u;    // ws is poisoned 0xAAAAAAAA -> "not ready"

// ws layout (floats):
//   aggT [kBH][kNC][kE]  — chunk vector totals
//   aggZ [kBH][kNC]      — chunk scalar totals
//   flag [kBH][kNC]      — uint ready flags (0xAAAAAAAA = not ready)
constexpr size_t kTOff = 0;
constexpr size_t kZOff = kTOff + (size_t)kBH * kNC * kE;
constexpr size_t kFOff = kZOff + (size_t)kBH * kNC;

// One single-wave block per (bh, chunk). All 2048 blocks co-resident
// (1 wave, ~0.2KB LDS, <128 VGPR -> 8 blocks/CU), so cross-block spin is
// deadlock-free. Lane l = output dim; lanes (2s,2s+1) split the K-dot.
__global__ __launch_bounds__(64)
void fused_scan(const float* __restrict__ keys, const float* __restrict__ values,
                const float* __restrict__ w_score, float* __restrict__ out,
                float* __restrict__ ws) {
  __shared__ float u_sh[kC];
  const int l  = threadIdx.x;
  const int c  = blockIdx.x & (kNC - 1);
  const int bh = blockIdx.x >> 6;           // kNC == 64
  const int b = bh >> 4, h = bh & 15;

  float* aggT = ws + kTOff + (size_t)bh * kNC * kE;
  float* aggZ = ws + kZOff + (size_t)bh * kNC;
  unsigned* flag = reinterpret_cast<unsigned*>(ws + kFOff) + (size_t)bh * kNC;

  // ---- u[s] = exp(scale * K[s].w_k), lanes (2s,2s+1) split the 64-dot ----
  const int sl = l >> 1;
  const int eh = (l & 1) * 32;
  const int s0 = c * kC;
  const float4* kr = reinterpret_cast<const float4*>(
      keys + ((size_t)(b * kL + s0 + sl) * kRow + h * kE + eh));
  const float4* wv4 = reinterpret_cast<const float4*>(w_score + kE + eh);
  float ax = 0.f, ay = 0.f, az = 0.f, aw = 0.f;
#pragma unroll
  for (int j = 0; j < 8; ++j) {
    const float4 kv = kr[j];
    const float4 wv = wv4[j];
    ax = fmaf(kv.x, wv.x, ax);
    ay = fmaf(kv.y, wv.y, ay);
    az = fmaf(kv.z, wv.z, az);
    aw = fmaf(kv.w, wv.w, aw);
  }
  float p = (ax + ay) + (az + aw);
  p += __shfl_xor(p, 1);
  const float u = __expf(p * kScale);   // no max-shift: p*scale ~ N(0,1)
  if (!(l & 1)) u_sh[sl] = u;

  // ---- V chunk into registers (lane = dim), local chunk totals ----
  const float* vp = values + ((size_t)(b * kL + s0) * kRow + h * kE) + l;
  float vreg[kC];
#pragma unroll
  for (int i = 0; i < kC; ++i) vreg[i] = vp[(size_t)i * kRow];
  __syncthreads();                       // u_sh visible

  float accL = 0.f, zL = 0.f;
#pragma unroll
  for (int i = 0; i < kC; ++i) {
    const float us = u_sh[i];
    accL = fmaf(us, vreg[i], accL);
    zL += us;
  }

  // ---- publish chunk aggregate (payload, fence, flag) ----
  aggT[(size_t)c * kE + l] = accL;
  if (l == 0) aggZ[c] = zL;
  __threadfence();
  if (l == 0)
    __hip_atomic_store(&flag[c], kReady, __ATOMIC_RELAXED, __HIP_MEMORY_SCOPE_AGENT);

  // ---- gather all predecessor aggregates (lane-parallel lookback) ----
  float runT = 0.f, runZ = 0.f;
  if (c > 0) {
    if (l < c) {
      while (__hip_atomic_load(&flag[l], __ATOMIC_RELAXED,
                               __HIP_MEMORY_SCOPE_AGENT) != kReady) {
        __builtin_amdgcn_s_sleep(1);
      }
    }
    __threadfence();                     // acquire: payloads now coherent
    float zj = (l < c) ? aggZ[l] : 0.f;
#pragma unroll
    for (int m = 32; m; m >>= 1) zj += __shfl_xor(zj, m);
    runZ = zj;
    for (int j = 0; j < c; ++j) runT += aggT[(size_t)j * kE + l];
  }

  // ---- replay chunk from registers, emit output ----
  float acc = runT, z = runZ;
  float* op = out + ((size_t)(b * kL + s0) * kRow + h * kE) + l;
#pragma unroll
  for (int i = 0; i < kC; ++i) {
    const float us = u_sh[i];
    acc = fmaf(us, vreg[i], acc);        // inclusive prefix P[l,d]
    z += us;                             // inclusive prefix Z[l]
    op[(size_t)i * kRow] = acc * __builtin_amdgcn_rcpf(z);
  }
}

}  // namespace

extern "C" void kernel_launch(void* const* d_in, const int* in_sizes, int n_in,
                              void* d_out, int out_size, void* d_ws, size_t ws_size,
                              hipStream_t stream) {
  // setup_inputs order: queries, keys, values, w_score, b_score.
  // queries and b_score cancel out of the softmax (shift invariance) — unused.
  const float* keys    = (const float*)d_in[1];
  const float* values  = (const float*)d_in[2];
  const float* w_score = (const float*)d_in[3];
  float* out = (float*)d_out;
  float* ws  = (float*)d_ws;
  (void)d_in; (void)in_sizes; (void)n_in; (void)out_size; (void)ws_size;

  fused_scan<<<kBH * kNC, 64, 0, stream>>>(keys, values, w_score, out, ws);
}

// Round 5
// 99.142 us; speedup vs baseline: 2.4520x; 2.4520x over previous
//
#include <hip/hip_runtime.h>
#include <math.h>

namespace {

constexpr int kB = 2, kL = 2048, kH = 16, kE = 64;
constexpr int kC  = 32;            // s-steps per chunk
constexpr int kNC = kL / kC;       // 64 chunks per (b,h)
constexpr int kBH = kB * kH;       // 32
constexpr int kRow = kH * kE;      // 1024 floats between consecutive s
constexpr float kScale = 0.125f;   // 1/sqrt(64)

// ws layout (floats):
//   u    [kBH][kL]       — exp(scale * K.w_k)
//   aggT [kBH][kNC][kE]  — chunk vector totals
//   aggZ [kBH][kNC]      — chunk scalar totals
constexpr size_t kUOff = 0;
constexpr size_t kTOff = (size_t)kBH * kL;
constexpr size_t kZOff = kTOff + (size_t)kBH * kNC * kE;

// ---- phase A: per (bh, chunk): u values + chunk totals ----
__global__ __launch_bounds__(64)
void phaseA(const float* __restrict__ keys, const float* __restrict__ values,
            const float* __restrict__ w_score, float* __restrict__ ws) {
  __shared__ float u_sh[kC];
  const int l  = threadIdx.x;
  const int c  = blockIdx.x & (kNC - 1);
  const int bh = blockIdx.x >> 6;           // kNC == 64
  const int b = bh >> 4, h = bh & 15;

  // lanes (2s, 2s+1) split the 64-dot for s = c*32 + (l>>1)
  const int sl = l >> 1;
  const int eh = (l & 1) * 32;
  const int s0 = c * kC;
  const float4* kr = reinterpret_cast<const float4*>(
      keys + ((size_t)(b * kL + s0 + sl) * kRow + h * kE + eh));
  const float4* wv4 = reinterpret_cast<const float4*>(w_score + kE + eh);
  float ax = 0.f, ay = 0.f, az = 0.f, aw = 0.f;
#pragma unroll
  for (int j = 0; j < 8; ++j) {
    const float4 kv = kr[j];
    const float4 wv = wv4[j];
    ax = fmaf(kv.x, wv.x, ax);
    ay = fmaf(kv.y, wv.y, ay);
    az = fmaf(kv.z, wv.z, az);
    aw = fmaf(kv.w, wv.w, aw);
  }
  float p = (ax + ay) + (az + aw);
  p += __shfl_xor(p, 1);                    // combine e-halves
  const float u = __expf(p * kScale);       // no max-shift: p*scale ~ N(0,1)
  if (!(l & 1)) {
    u_sh[sl] = u;
    ws[kUOff + (size_t)bh * kL + s0 + sl] = u;
  }
  __syncthreads();

  // chunk totals: lane = output dim
  float acc = 0.f, z = 0.f;
  const float* vp = values + ((size_t)(b * kL + s0) * kRow + h * kE) + l;
#pragma unroll
  for (int i = 0; i < kC; ++i) {
    const float us = u_sh[i];
    acc = fmaf(us, vp[(size_t)i * kRow], acc);
    z += us;
  }
  ws[kTOff + ((size_t)bh * kNC + c) * kE + l] = acc;
  if (l == 0) ws[kZOff + (size_t)bh * kNC + c] = z;
}

// ---- phase C: gather exclusive prefix + replay chunk, emit output ----
__global__ __launch_bounds__(64)
void phaseC(const float* __restrict__ values, const float* __restrict__ ws,
            float* __restrict__ out) {
  __shared__ float u_sh[kC];
  const int l  = threadIdx.x;
  const int c  = blockIdx.x & (kNC - 1);
  const int bh = blockIdx.x >> 6;
  const int b = bh >> 4, h = bh & 15;

  if (l < kC) u_sh[l] = ws[kUOff + (size_t)bh * kL + c * kC + l];

  // exclusive T prefix: 8 independent accumulators to pipeline the loads
  const float* aggT = ws + kTOff + (size_t)bh * kNC * kE;
  float t0 = 0.f, t1 = 0.f, t2 = 0.f, t3 = 0.f,
        t4 = 0.f, t5 = 0.f, t6 = 0.f, t7 = 0.f;
  int j = 0;
  for (; j + 8 <= c; j += 8) {
    t0 += aggT[(size_t)(j + 0) * kE + l];
    t1 += aggT[(size_t)(j + 1) * kE + l];
    t2 += aggT[(size_t)(j + 2) * kE + l];
    t3 += aggT[(size_t)(j + 3) * kE + l];
    t4 += aggT[(size_t)(j + 4) * kE + l];
    t5 += aggT[(size_t)(j + 5) * kE + l];
    t6 += aggT[(size_t)(j + 6) * kE + l];
    t7 += aggT[(size_t)(j + 7) * kE + l];
  }
  for (; j < c; ++j) t0 += aggT[(size_t)j * kE + l];
  float acc = ((t0 + t1) + (t2 + t3)) + ((t4 + t5) + (t6 + t7));

  // exclusive Z prefix: lane-parallel load + wave reduce (kNC == 64 lanes)
  const float* aggZ = ws + kZOff + (size_t)bh * kNC;
  float zj = (l < c) ? aggZ[l] : 0.f;
#pragma unroll
  for (int m = 32; m; m >>= 1) zj += __shfl_xor(zj, m);
  float z = zj;

  __syncthreads();                          // u_sh visible

  const size_t base = (size_t)(b * kL + c * kC) * kRow + h * kE + l;
  const float* vp = values + base;
  float* op = out + base;
#pragma unroll
  for (int i = 0; i < kC; ++i) {
    const float us = u_sh[i];
    acc = fmaf(us, vp[(size_t)i * kRow], acc);   // inclusive prefix P[l,d]
    z += us;                                      // inclusive prefix Z[l]
    op[(size_t)i * kRow] = acc * __builtin_amdgcn_rcpf(z);
  }
}

}  // namespace

extern "C" void kernel_launch(void* const* d_in, const int* in_sizes, int n_in,
                              void* d_out, int out_size, void* d_ws, size_t ws_size,
                              hipStream_t stream) {
  // setup_inputs order: queries, keys, values, w_score, b_score.
  // queries and b_score cancel out of the softmax (shift invariance) — unused.
  const float* keys    = (const float*)d_in[1];
  const float* values  = (const float*)d_in[2];
  const float* w_score = (const float*)d_in[3];
  float* out = (float*)d_out;
  float* ws  = (float*)d_ws;
  (void)d_in; (void)in_sizes; (void)n_in; (void)out_size; (void)ws_size;

  phaseA<<<kBH * kNC, 64, 0, stream>>>(keys, values, w_score, ws);
  phaseC<<<kBH * kNC, 64, 0, stream>>>(values, ws, out);
}